// Round 15
// baseline (46.235 us; speedup 1.0000x reference)
//
#include <hip/hip_runtime.h>
#include <hip/hip_bf16.h>

// DisenGCN forward — 2-dispatch chain, 8-blocks/side routing, gen-tagged sync
// with f24x2-packed slots (one u64 atomic carries TWO floats + 16-bit gen):
//   K1 (chip-wide): gather -> z0=proj(W0) -> znbA [bf16 norm]; neighbors also
//                   z1=proj(W1,z0) -> znbB [bf16 norm]. Bumps call_ctr.
//   K2 (16 blocks = 8/side x 1024 thr): 6 routing sweeps. Per sweep:
//       partial (64 f32) -> 32 x atomicExch(u64{f24,f24,gen16}) by wv0 lanes<32
//       readers: waves 0..3, wave w covers partials {2w, 2w+1} (lanes 0-31 /
//       32-63), each lane one u64 RMW-poll until gen matches -> unpack 2 f32
//       -> LDS. No fences, no flags, no pre-zero (gen fresh per call/replay).
//       s==2: row-0 proj(W1). s==5: block(0,0) reads all 16 partials (8 waves,
//       one u64 per lane) and finalizes.
//
// f24 = f32 with low 8 mantissa bits truncated (rel err ~1.5e-5, negligible vs
// bf16 znb storage). gen16 = (call_ctr*8+s+1)&0xffff: unique across replays.
//
// Route layout: 8 lanes/row; lane j=lane&7 holds elems [8j..8j+7]; channel
// k=j>>1. Ego in sEgo normalized AND pre-scaled by log2(e) (exp2 softmax).
//
// ws: znbA[2*n_rows*64 bf16] | znbB[same] | slots[6*2*SPB*32 u64] | call_ctr

#define EPS 1e-12f
#define LOG2E 1.44269504088896f
#define SPB 8              // blocks per side in K2
#define NBK (2 * SPB)

__device__ __forceinline__ float g16sum(float v) {
    v += __shfl_xor(v, 1, 64);
    v += __shfl_xor(v, 2, 64);
    v += __shfl_xor(v, 4, 64);
    v += __shfl_xor(v, 8, 64);
    return v;
}
__device__ __forceinline__ unsigned short f2bf(float f) {  // RNE
    unsigned int b = __float_as_uint(f);
    b += 0x7fffu + ((b >> 16) & 1u);
    return (unsigned short)(b >> 16);
}
__device__ __forceinline__ float bf2f(unsigned short u) {
    return __uint_as_float(((unsigned int)u) << 16);
}
__device__ __forceinline__ float bflo(unsigned int w) {
    return __uint_as_float(w << 16);
}
__device__ __forceinline__ float bfhi(unsigned int w) {
    return __uint_as_float(w & 0xffff0000u);
}

__device__ __forceinline__ unsigned long long pack2(float f0, float f1,
                                                    unsigned int gen16) {
    const unsigned long long a = __float_as_uint(f0) >> 8;   // top 24 bits
    const unsigned long long b = __float_as_uint(f1) >> 8;
    return (a << 40) | (b << 16) | (unsigned long long)gen16;
}
__device__ __forceinline__ float unpack0(unsigned long long v) {
    return __uint_as_float((unsigned int)(v >> 40) << 8);
}
__device__ __forceinline__ float unpack1(unsigned long long v) {
    return __uint_as_float(((unsigned int)(v >> 16) & 0xffffffu) << 8);
}
// poll element until its gen16 matches; returns the whole word
__device__ __forceinline__ unsigned long long slot_poll(unsigned long long* p,
                                                        unsigned int gen16) {
    unsigned long long v;
    for (;;) {
        v = atomicAdd(p, 0ull);                       // 64-bit RMW read
        if ((unsigned int)(v & 0xffffull) == gen16) break;
        __builtin_amdgcn_s_sleep(1);
    }
    return v;
}

__device__ __forceinline__ float proj_row4(const float xa[4],
                                           const float* __restrict__ W,
                                           const float* __restrict__ b, int lane) {
    const int k = lane >> 4, d = lane & 15;
    float sum = b[k * 16 + d];
    const float* __restrict__ Wp = W + k * 1024 + d;  // W[k][i][d]
#pragma unroll
    for (int i = 0; i < 64; ++i)
        sum = fmaf(__shfl(xa[i & 3], i >> 2, 64), Wp[i * 16], sum);
    return fmaxf(sum, 0.f);
}

// ---- K1: gather + proj L0 + (neighbors) proj L1; bump call_ctr ----
__global__ __launch_bounds__(256) void k1_gather_proj2(
    const int* __restrict__ user, const int* __restrict__ item,
    const int* __restrict__ nu, const int* __restrict__ ni,
    const float* __restrict__ Gu, const float* __restrict__ Gi,
    const float* __restrict__ W0, const float* __restrict__ b0,
    const float* __restrict__ W1, const float* __restrict__ b1,
    unsigned short* __restrict__ znbA, unsigned short* __restrict__ znbB,
    unsigned int* __restrict__ call_ctr, int n_rows)
{
    if (blockIdx.x == 0 && threadIdx.x == 0) atomicAdd(call_ctr, 1u);

    const int lane = threadIdx.x & 63;
    const int wv   = threadIdx.x >> 6;
    const int rr   = blockIdx.x * 4 + wv;
    if (rr >= 2 * n_rows) return;
    const int side = rr >= n_rows;
    const int n    = rr - side * n_rows;
    const int c    = lane & 15;

    int idx; const float* G;
    if (n == 0) { idx = side ? item[0] : user[0];     G = side ? Gi : Gu; }
    else        { idx = side ? ni[n - 1] : nu[n - 1]; G = side ? Gu : Gi; }
    const float4 xv = ((const float4*)(G + (size_t)idx * 64))[c];
    const float xa[4] = {xv.x, xv.y, xv.z, xv.w};

    const float z0 = proj_row4(xa, W0, b0, lane);
    const float nrm0 = fmaxf(sqrtf(g16sum(z0 * z0)), EPS);
    znbA[(size_t)rr * 64 + lane] = f2bf(z0 / nrm0);

    if (n == 0) return;  // row 0's L1 input is the routed result (K2)

    float xa2[4];
#pragma unroll
    for (int jj = 0; jj < 4; ++jj) xa2[jj] = __shfl(z0, (c << 2) | jj, 64);
    const float z1 = proj_row4(xa2, W1, b1, lane);
    const float nrm1 = fmaxf(sqrtf(g16sum(z1 * z1)), EPS);
    znbB[(size_t)rr * 64 + lane] = f2bf(z1 / nrm1);
}

// ---- K2: 6 routing sweeps across 8 blocks/side + fused finalize ----
__global__ __launch_bounds__(1024) void k2_route_all(
    const unsigned short* __restrict__ znbA, const unsigned short* __restrict__ znbB,
    const float* __restrict__ W1, const float* __restrict__ b1,
    unsigned long long* __restrict__ slots,
    const unsigned int* __restrict__ call_ctr,
    float* __restrict__ out, int n_neigh)
{
    const int n_rows = n_neigh + 1;
    const int tid  = threadIdx.x;
    const int lane = tid & 63;
    const int wv   = tid >> 6;
    const int side = blockIdx.x & 1;
    const int bg   = blockIdx.x >> 1;
    const unsigned short* __restrict__ zA = znbA + (size_t)side * n_rows * 64;
    const unsigned short* __restrict__ zB = znbB + (size_t)side * n_rows * 64;
    const unsigned int genbase = (*call_ctr) * 8u;   // dispatch-boundary read

    __shared__ float sW[4096];   // W1 i-major: sW[i*64 + m]
    __shared__ float red[16][64];
    __shared__ float sEgo[64];
    __shared__ float sTmp[64];

    for (int q = tid; q < 4096; q += 1024) {
        const int i = q >> 6, m = q & 63;
        sW[q] = W1[(m >> 4) * 1024 + i * 16 + (m & 15)];
    }
    if (tid < 64) sEgo[tid] = bf2f(zA[tid]) * LOG2E;  // normalized row 0
    __syncthreads();

    const int j   = lane & 7;
    const int rg0 = bg * 128 + (tid >> 3);   // this block's first row offset

    for (int s = 0; s < 6; ++s) {
        const unsigned short* __restrict__ zb = (s < 3) ? zA : zB;
        const unsigned int gen = (genbase + (unsigned int)s + 1u) & 0xffffu;
        float ego[8];
#pragma unroll
        for (int m = 0; m < 8; ++m) ego[m] = sEgo[j * 8 + m];

        float a8[8] = {0.f, 0.f, 0.f, 0.f, 0.f, 0.f, 0.f, 0.f};
        for (int r = rg0; r < n_neigh; r += SPB * 128) {
            const uint4 q = *(const uint4*)(zb + (((size_t)r + 1) << 6) + (j << 3));
            float x[8];
            x[0] = bflo(q.x); x[1] = bfhi(q.x);
            x[2] = bflo(q.y); x[3] = bfhi(q.y);
            x[4] = bflo(q.z); x[5] = bfhi(q.z);
            x[6] = bflo(q.w); x[7] = bfhi(q.w);
            float partial = 0.f;
#pragma unroll
            for (int m = 0; m < 8; ++m) partial = fmaf(x[m], ego[m], partial);
            const float dp = partial + __shfl_xor(partial, 1, 64);  // ch dot * log2e
            const float eo = exp2f(dp);
            float den = eo + __shfl_xor(eo, 2, 64);
            den += __shfl_xor(den, 4, 64);                          // all 4 channels
            const float p = eo * __builtin_amdgcn_rcpf(den);
#pragma unroll
            for (int m = 0; m < 8; ++m) a8[m] = fmaf(p, x[m], a8[m]);
        }
#pragma unroll
        for (int mask = 8; mask <= 32; mask <<= 1)
#pragma unroll
            for (int m = 0; m < 8; ++m) a8[m] += __shfl_xor(a8[m], mask, 64);
        if (lane < 8) {
#pragma unroll
            for (int m = 0; m < 8; ++m) red[wv][lane * 8 + m] = a8[m];
        }
        __syncthreads();                                  // (1) red complete

        unsigned long long* slotbase = slots + (size_t)(s * 2 + side) * SPB * 32;
        if (wv == 0) {
            float ssum = 0.f;
#pragma unroll
            for (int w = 0; w < 16; ++w) ssum += red[w][lane];
            // pack cols {2e, 2e+1} into lane e<32 (shfls with ALL lanes active)
            const float f0 = __shfl(ssum, (lane & 31) * 2, 64);
            const float f1 = __shfl(ssum, (lane & 31) * 2 + 1, 64);
            if (lane < 32)
                atomicExch(&slotbase[bg * 32 + lane], pack2(f0, f1, gen));
        }
        __syncthreads();                                  // (2) red reusable

        if (s < 5) {
            if (wv < 4) {                                 // wave w: partials 2w,2w+1
                const int p = 2 * wv + (lane >> 5);
                const int e = lane & 31;
                const unsigned long long v = slot_poll(&slotbase[p * 32 + e], gen);
                ((float2*)red[p])[e] = make_float2(unpack0(v), unpack1(v));
            }
            __syncthreads();                              // (3) partials in LDS
            if (wv == 0) {
                float e = 0.f;
#pragma unroll
                for (int bb = 0; bb < SPB; ++bb) e += red[bb][lane];
                if (s == 2) sTmp[lane] = e;               // raw routed L0
                else sEgo[lane] = (e / fmaxf(sqrtf(g16sum(e * e)), EPS)) * LOG2E;
            }
            __syncthreads();                              // (4) ego ready
            if (s == 2) {
                if (wv == 0) {                            // row-0 proj(W1)
                    float xa[4];
#pragma unroll
                    for (int jj = 0; jj < 4; ++jj) xa[jj] = sTmp[((lane & 15) << 2) | jj];
                    float sum = b1[lane];
#pragma unroll
                    for (int i = 0; i < 64; ++i)
                        sum = fmaf(__shfl(xa[i & 3], i >> 2, 64), sW[i * 64 + lane], sum);
                    sum = fmaxf(sum, 0.f);
                    sEgo[lane] = (sum / fmaxf(sqrtf(g16sum(sum * sum)), EPS)) * LOG2E;
                }
                __syncthreads();                          // (5)
            }
        } else if (side == 0 && bg == 0) {
            // finalize: 8 waves read all 16 partials (512 u64, 1 per lane)
            const int g  = wv * 64 + lane;                // [0, 512)
            const int s2 = g >> 8;                        // side
            const int pp = (g >> 5) & 7;                  // partial within side
            const int e  = g & 31;
            unsigned long long* sb2 = slots + (size_t)(5 * 2 + s2) * SPB * 32;
            if (wv < 8) {
                const unsigned long long v = slot_poll(&sb2[pp * 32 + e], gen);
                ((float2*)red[s2 * 8 + pp])[e] = make_float2(unpack0(v), unpack1(v));
            }
            __syncthreads();
            if (wv == 0) {
                float u = 0.f, v = 0.f;
#pragma unroll
                for (int w = 0; w < 8; ++w)  u += red[w][lane];
#pragma unroll
                for (int w = 8; w < 16; ++w) v += red[w][lane];
                out[1 + lane]  = u;
                out[65 + lane] = v;
                float p = u * v;
#pragma unroll
                for (int sh = 32; sh >= 1; sh >>= 1) p += __shfl_xor(p, sh, 64);
                if (lane == 0) out[0] = p;
            }
        }
    }
}

extern "C" void kernel_launch(void* const* d_in, const int* in_sizes, int n_in,
                              void* d_out, int out_size, void* d_ws, size_t ws_size,
                              hipStream_t stream) {
    const int*   user       = (const int*)d_in[0];
    const int*   item       = (const int*)d_in[1];
    const int*   neigh_user = (const int*)d_in[2];
    const int*   neigh_item = (const int*)d_in[3];
    const float* Gu         = (const float*)d_in[4];
    const float* Gi         = (const float*)d_in[5];
    const float* W0         = (const float*)d_in[6];
    const float* b0         = (const float*)d_in[7];
    const float* W1         = (const float*)d_in[8];
    const float* b1         = (const float*)d_in[9];
    float* out = (float*)d_out;

    const int n_neigh = in_sizes[2];
    const int n_rows  = n_neigh + 1;
    const size_t rowsz = (size_t)2 * n_rows * 64;

    unsigned short*     znbA  = (unsigned short*)d_ws;
    unsigned short*     znbB  = znbA + rowsz;
    unsigned long long* slots = (unsigned long long*)(znbB + rowsz);
    unsigned int*       ctr   = (unsigned int*)(slots + 6 * 2 * SPB * 32);

    hipLaunchKernelGGL(k1_gather_proj2, dim3((2 * n_rows + 3) / 4), dim3(256), 0, stream,
                       user, item, neigh_user, neigh_item, Gu, Gi, W0, b0, W1, b1,
                       znbA, znbB, ctr, n_rows);
    hipLaunchKernelGGL(k2_route_all, dim3(NBK), dim3(1024), 0, stream,
                       znbA, znbB, W1, b1, slots, ctr, out, n_neigh);
}